// Round 15
// baseline (240.049 us; speedup 1.0000x reference)
//
#include <hip/hip_runtime.h>

typedef __attribute__((ext_vector_type(8))) short bf16x8;
typedef __attribute__((ext_vector_type(4))) float f32x4;

#define FROW   4224                     // 66 cols * 64 B per LDS feature row
#define FBUF4  25344                    // 6 rows (4-row block + halo)
#define BTRIO  12288                    // 3 taps * 4096 B
#define LDS_T2 (2 * FBUF4 + 2 * BTRIO)  // 75264 B -> 2 blocks/CU

static __device__ __forceinline__ unsigned short f2bf(float f) {
  union { float f; unsigned u; } v; v.f = f;
  unsigned r = v.u + 0x7fffu + ((v.u >> 16) & 1u);
  return (unsigned short)(r >> 16);
}

static __device__ __forceinline__ float bfhi2f(unsigned u) {  // hi 16 bits as bf16
  union { unsigned u; float f; } t; t.u = u & 0xffff0000u; return t.f;
}
static __device__ __forceinline__ float bflo2f(unsigned u) {  // lo 16 bits as bf16
  union { unsigned u; float f; } t; t.u = u << 16; return t.f;
}

static __device__ __forceinline__ void gload16(const void* g, void* l) {
  __builtin_amdgcn_global_load_lds(
      (const __attribute__((address_space(1))) void*)g,
      (__attribute__((address_space(3))) void*)l, 16, 0, 0);
}

// ---------------- kernel P: pack weights ----------------
// wpk: [it(126 = c2*9+tap)][co(64)][slot(4)][8ci] bf16, slot' = slot ^ ((co>>1)&3)
__global__ void pack_w_k(const float* __restrict__ sb, const float* __restrict__ ss,
                         const float* __restrict__ cf, unsigned short* __restrict__ wpk) {
  int idx = blockIdx.x * 256 + threadIdx.x;
  if (idx >= 126 * 64 * 32) return;
  int e = idx & 7;
  int q = (idx >> 3) & 3;
  int co = (idx >> 5) & 63;
  int rest = idx >> 11;
  int tap = rest % 9;
  int c2 = rest / 9;
  int c = c2 >> 1, half = c2 & 1;
  int ci = half * 32 + q * 8 + e;
  int kh = tap / 3, kw = tap % 3;
  int wi = ((co * 64 + ci) * 3 + kh) * 3 + kw;
  float v;
  if (c == 0) {
    v = sb[wi];
  } else {
    int s = (c - 1) / 3, g = (c - 1) % 3;
    v = cf[(s * 36864 + wi) * 3 + g] * ss[wi];
  }
  wpk[((c2 * 9 + tap) * 64 + co) * 32 + ((q ^ ((co >> 1) & 3)) << 3) + e] = f2bf(v);
}

// ---------------- kernel G: fused featgen + GEMM, bf16-packed x registers ----------------
// grid (32 b, 16 hg) = 512 blocks = 2/CU (LDS 75.3 KB). 4 waves; wave wid owns
// image row h0+wid: M=64 px x N=64 co, all 9 taps. x window held in registers
// as 48 packed u32 (bf16 pairs: lo=half0, hi=half1), loaded once in prologue.
// Featgen per chunk is pure VALU/TRANS from registers -> swizzled ds_write_b128.
// __launch_bounds__(256,1): lift VGPR cap so ~180 live regs don't spill (R14
// lesson: (256,2) made the allocator pin 128 and spill 264 MB to scratch).
__global__ __launch_bounds__(256, 1) void gemm_k(
    const float* __restrict__ x, const unsigned short* __restrict__ wpk,
    const float* __restrict__ bias, float* __restrict__ out) {
  extern __shared__ __align__(16) char smem[];
  const int b = blockIdx.x;
  const int h0 = blockIdx.y * 4;
  const int tid = threadIdx.x;
  const int lane = tid & 63;
  const int wid = tid >> 6;          // 0..3
  const int l15 = lane & 15;
  const int lg = lane >> 4;
  const char* wpkB = (const char*)wpk;

  // featgen thread map: w = tid&63 (lane=w), fq = ci-quad-within-half = tid>>6
  const int fw = tid & 63;
  const int fq = tid >> 6;
  const int fcol = fw + 1;                               // LDS col (halo 0/65)
  const int fsl16 = (fq ^ ((fcol >> 1) & 3)) << 4;       // swizzled slot byte-off
  const int fbase = fcol * 64 + fsl16;

  // zero never-staged bytes: halo cols + out-of-range rows (both feat buffers)
  for (int i = tid; i < 2 * FBUF4 / 4; i += 256) {
    int off = i * 4;
    int off2 = (off >= FBUF4) ? off - FBUF4 : off;
    int row = off2 / FROW;
    int cb = off2 - row * FROW;
    int hh = h0 - 1 + row;
    bool staged = ((unsigned)hh < 64u) && (cb >= 64) && (cb < 4160);
    if (!staged) ((int*)smem)[i] = 0;
  }

  // ---- prologue: block's x window -> 48 packed bf16-pair registers ----
  const float* xb = x + (size_t)(b * 64 + fq * 8) * 4096 + fw;
  unsigned xp[6][8];
#pragma unroll
  for (int r = 0; r < 6; ++r) {
    int hh = h0 - 1 + r;
    if ((unsigned)hh < 64u) {
#pragma unroll
      for (int e = 0; e < 8; ++e) {
        float v0 = xb[(size_t)e * 4096 + hh * 64];
        float v1 = xb[(size_t)(32 + e) * 4096 + hh * 64];
        xp[r][e] = ((unsigned)f2bf(v1) << 16) | (unsigned)f2bf(v0);
      }
    } else {
#pragma unroll
      for (int e = 0; e < 8; ++e) xp[r][e] = 0u;
    }
  }

  // hoisted swizzled LDS offsets
  int aoff[4][3], boff[4];
#pragma unroll
  for (int cf = 0; cf < 4; ++cf) {
#pragma unroll
    for (int kw = 0; kw < 3; ++kw) {
      int col = cf * 16 + l15 + kw;
      aoff[cf][kw] = col * 64 + ((lg ^ ((col >> 1) & 3)) << 4);
    }
    int co = cf * 16 + l15;
    boff[cf] = co * 64 + ((lg ^ ((co >> 1) & 3)) << 4);
  }

  // stage B trio for (chunk cn, kh khn) into bdst: 12 gload16 over 4 waves
#define STAGE_TRIO(cn, khn, bdst)                                                \
  _Pragma("unroll")                                                              \
  for (int i = 0; i < 3; ++i) {                                                  \
    int u = i * 4 + wid;                                                         \
    gload16(wpkB + (size_t)((cn) * 9 + (khn) * 3 + (u >> 2)) * 4096 +            \
                (u & 3) * 1024 + lane * 16,                                      \
            (bdst) + (u >> 2) * 4096 + (u & 3) * 1024);                          \
  }

  // featgen from registers: rows 2p,2p+1 of chunk cn (half H compile-time) -> fdst
#define FEATGEN_P(cn, p, fdst, H)                                                \
  {                                                                              \
    const int c_ = (cn) >> 1;                                                    \
    _Pragma("unroll")                                                            \
    for (int rr = 0; rr < 2; ++rr) {                                             \
      const int r = (p) * 2 + rr;                                                \
      int hh = h0 - 1 + r;                                                       \
      if ((unsigned)hh < 64u) {                                                  \
        bf16x8 pk;                                                               \
        _Pragma("unroll")                                                        \
        for (int e = 0; e < 8; ++e) {                                            \
          float v = (H) ? bfhi2f(xp[r][e]) : bflo2f(xp[r][e]);                   \
          float val;                                                             \
          if (c_ == 0)      val = v / (1.0f + __expf(-v));                       \
          else if (c_ == 1) val = __cosf(v);                                     \
          else if (c_ == 2) val = __cosf(2.0f * v);                              \
          else if (c_ == 3) val = __cosf(3.0f * v);                              \
          else if (c_ == 4) val = __sinf(v);                                     \
          else if (c_ == 5) val = __sinf(2.0f * v);                              \
          else              val = __sinf(3.0f * v);                              \
          pk[e] = (short)f2bf(val);                                              \
        }                                                                        \
        *(bf16x8*)((fdst) + r * FROW + fbase) = pk;                              \
      }                                                                          \
    }                                                                            \
  }

  // prologue: features chunk 0 (half 0, all 3 phases) + B trio (0,0)
#pragma unroll
  for (int p = 0; p < 3; ++p) { FEATGEN_P(0, p, smem, 0) }
  STAGE_TRIO(0, 0, smem + 2 * FBUF4)
  __syncthreads();

  f32x4 acc[4][4];
#pragma unroll
  for (int cfi = 0; cfi < 4; ++cfi)
#pragma unroll
    for (int nf = 0; nf < 4; ++nf)
#pragma unroll
      for (int qq = 0; qq < 4; ++qq) acc[cfi][nf][qq] = 0.0f;

  for (int c2 = 0; c2 < 14; ++c2) {
    const char* f = smem + ((c2 & 1) ? FBUF4 : 0);
    char* fnext = smem + (((c2 + 1) & 1) ? FBUF4 : 0);
#pragma unroll
    for (int kh = 0; kh < 3; ++kh) {
      const int khg = c2 * 3 + kh;
      const char* bb = smem + 2 * FBUF4 + ((khg & 1) ? BTRIO : 0);
      if (khg < 41) {
        char* bnext = smem + 2 * FBUF4 + (((khg + 1) & 1) ? BTRIO : 0);
        const int cn = (khg + 1) / 3, khn = (khg + 1) % 3;
        STAGE_TRIO(cn, khn, bnext)
      }
      if (c2 < 13) {
        const int cn = c2 + 1;
        if (cn & 1) { FEATGEN_P(cn, kh, fnext, 1) }
        else        { FEATGEN_P(cn, kh, fnext, 0) }
      }

      const char* frow = f + (wid + kh) * FROW;
#pragma unroll
      for (int kw = 0; kw < 3; ++kw) {
        bf16x8 A[4], Bv[4];
#pragma unroll
        for (int cfi = 0; cfi < 4; ++cfi)
          A[cfi] = *(const bf16x8*)(frow + aoff[cfi][kw]);
#pragma unroll
        for (int nf = 0; nf < 4; ++nf)
          Bv[nf] = *(const bf16x8*)(bb + kw * 4096 + boff[nf]);
#pragma unroll
        for (int cfi = 0; cfi < 4; ++cfi)
#pragma unroll
          for (int nf = 0; nf < 4; ++nf)
            acc[cfi][nf] = __builtin_amdgcn_mfma_f32_16x16x32_bf16(
                A[cfi], Bv[nf], acc[cfi][nf], 0, 0, 0);
      }
      __syncthreads();
    }
  }
#undef STAGE_TRIO
#undef FEATGEN_P

  // epilogue: direct store. C/D: col(l15)=co, row=lg*4+reg = pixel w
  const int h = h0 + wid;
#pragma unroll
  for (int cfi = 0; cfi < 4; ++cfi) {
    int w4 = cfi * 16 + (lg << 2);
#pragma unroll
    for (int nf = 0; nf < 4; ++nf) {
      int co = nf * 16 + l15;
      float bv = bias[co];
      f32x4 v = acc[cfi][nf];
      f32x4 res;
      res[0] = v[0] + bv; res[1] = v[1] + bv; res[2] = v[2] + bv; res[3] = v[3] + bv;
      *(f32x4*)(out + ((size_t)(b * 64 + co) * 64 + h) * 64 + w4) = res;
    }
  }
}

// ---------------- fallback: naive fp32 direct (if ws too small) ----------------
__global__ void naive_k(const float* __restrict__ x, const float* __restrict__ sb,
                        const float* __restrict__ ss, const float* __restrict__ cf,
                        const float* __restrict__ bias, float* __restrict__ out) {
  int idx = blockIdx.x * 256 + threadIdx.x;
  if (idx >= 32 * 64 * 64 * 64) return;
  int w = idx & 63, h = (idx >> 6) & 63, co = (idx >> 12) & 63, b = idx >> 18;
  float acc = bias[co];
  for (int ci = 0; ci < 64; ++ci) {
    for (int kh = 0; kh < 3; ++kh) {
      int hh = h + kh - 1;
      if ((unsigned)hh >= 64u) continue;
      for (int kw = 0; kw < 3; ++kw) {
        int ww = w + kw - 1;
        if ((unsigned)ww >= 64u) continue;
        float v = x[((b * 64 + ci) * 64 + hh) * 64 + ww];
        int wi = ((co * 64 + ci) * 3 + kh) * 3 + kw;
        float s1, c1; __sincosf(v, &s1, &c1);
        float c2 = c1 * c1 - s1 * s1, s2 = 2.f * s1 * c1;
        float c3 = c1 * c2 - s1 * s2, s3 = s1 * c2 + c1 * s2;
        float t = sb[wi] * (v / (1.f + __expf(-v)));
        t += ss[wi] * (cf[wi * 3] * c1 + cf[wi * 3 + 1] * c2 + cf[wi * 3 + 2] * c3 +
                       cf[(36864 + wi) * 3] * s1 + cf[(36864 + wi) * 3 + 1] * s2 +
                       cf[(36864 + wi) * 3 + 2] * s3);
        acc += t;
      }
    }
  }
  out[idx] = acc;
}

extern "C" void kernel_launch(void* const* d_in, const int* in_sizes, int n_in,
                              void* d_out, int out_size, void* d_ws, size_t ws_size,
                              hipStream_t stream) {
  const float* x = (const float*)d_in[0];
  const float* sb = (const float*)d_in[1];
  const float* ss = (const float*)d_in[2];
  const float* cf = (const float*)d_in[3];
  const float* bias = (const float*)d_in[4];
  float* out = (float*)d_out;

  const size_t NEED = 1u << 20;   // only wpk (516 KB)
  if (ws_size >= NEED) {
    unsigned short* wpk = (unsigned short*)d_ws;
    pack_w_k<<<1008, 256, 0, stream>>>(sb, ss, cf, wpk);
    (void)hipFuncSetAttribute((const void*)gemm_k,
                              hipFuncAttributeMaxDynamicSharedMemorySize, LDS_T2);
    gemm_k<<<dim3(32, 16), 256, LDS_T2, stream>>>(x, wpk, bias, out);
  } else {
    naive_k<<<32768, 256, 0, stream>>>(x, sb, ss, cf, bias, out);
  }
}

// Round 16
// 91.766 us; speedup vs baseline: 2.6159x; 2.6159x over previous
//
#include <hip/hip_runtime.h>

typedef __attribute__((ext_vector_type(8))) short bf16x8;
typedef __attribute__((ext_vector_type(4))) float f32x4;

#define FROW   4224                     // 66 cols * 64 B per LDS feature row
#define FBUF4  25344                    // 6 rows (4-row block + halo)
#define BTRIO  12288                    // 3 taps * 4096 B
#define LDS_T2 (2 * FBUF4 + 2 * BTRIO)  // 75264 B -> 2 blocks/CU

static __device__ __forceinline__ unsigned short f2bf(float f) {
  union { float f; unsigned u; } v; v.f = f;
  unsigned r = v.u + 0x7fffu + ((v.u >> 16) & 1u);
  return (unsigned short)(r >> 16);
}

static __device__ __forceinline__ void gload16(const void* g, void* l) {
  __builtin_amdgcn_global_load_lds(
      (const __attribute__((address_space(1))) void*)g,
      (__attribute__((address_space(3))) void*)l, 16, 0, 0);
}

// ---------------- kernel F: feature expansion + fused weight pack ----------------
// fg: [c2(14)][b(32)][h(64)][w(64)][slot(4)][8ci] bf16, slot' = slot ^ (((w+1)>>1)&3)
// wpk: [it(126)][co(64)][slot(4)][8ci] bf16, slot' = slot ^ ((co>>1)&3)
__global__ void feats_k(const float* __restrict__ x, const float* __restrict__ sb,
                        const float* __restrict__ ss, const float* __restrict__ cf,
                        unsigned short* __restrict__ fg, unsigned short* __restrict__ wpk) {
  __shared__ __align__(16) unsigned short lds[64 * 456];
  const int b = blockIdx.x, h = blockIdx.y;
  const int tid = threadIdx.x;             // 256
  const int w = tid & 63, cig = tid >> 6;
  const int key = ((w + 1) >> 1) & 3;
  const int base = w * 456;
#pragma unroll
  for (int i = 0; i < 16; ++i) {
    int ci = cig * 16 + i;
    float v = x[(((size_t)b * 64 + ci) * 64 + h) * 64 + w];
    float sg = 1.0f / (1.0f + __expf(-v));
    float f0 = v * sg;
    float s1, c1;
    __sincosf(v, &s1, &c1);
    float c2v = c1 * c1 - s1 * s1, s2v = 2.0f * s1 * c1;
    float c3v = c1 * c2v - s1 * s2v, s3v = s1 * c2v + c1 * s2v;
    int q = ci >> 3;
    int half = q >> 2, qq = q & 3;
    int sl = (half * 4 + (qq ^ key)) * 8 + (ci & 7);
    lds[base + 0 * 64 + sl] = f2bf(f0);
    lds[base + 1 * 64 + sl] = f2bf(c1);
    lds[base + 2 * 64 + sl] = f2bf(c2v);
    lds[base + 3 * 64 + sl] = f2bf(c3v);
    lds[base + 4 * 64 + sl] = f2bf(s1);
    lds[base + 5 * 64 + sl] = f2bf(s2v);
    lds[base + 6 * 64 + sl] = f2bf(s3v);
  }
  __syncthreads();
#pragma unroll
  for (int k = 0; k < 14; ++k) {
    int u = tid + k * 256;
    int qs = u & 3;
    int ww = (u >> 2) & 63;
    int c2i = u >> 8;
    int cc = c2i >> 1, half = c2i & 1;
    uint4 v = *(const uint4*)&lds[ww * 456 + cc * 64 + (half * 4 + qs) * 8];
    unsigned short* dst = fg + ((size_t)(c2i * 32 + b) * 64 + h) * 2048 + (ww * 4 + qs) * 8;
    *(uint4*)dst = v;
  }
  if (tid < 126) {   // fused weight pack: 126 items per block
    int idx = (b * 64 + h) * 126 + tid;
    int e = idx & 7;
    int q = (idx >> 3) & 3;
    int co = (idx >> 5) & 63;
    int rest = idx >> 11;
    int tap = rest % 9;
    int c2p = rest / 9;
    int c = c2p >> 1, half = c2p & 1;
    int ci = half * 32 + q * 8 + e;
    int kh = tap / 3, kw = tap % 3;
    int wi = ((co * 64 + ci) * 3 + kh) * 3 + kw;
    float v;
    if (c == 0) {
      v = sb[wi];
    } else {
      int s = (c - 1) / 3, g = (c - 1) % 3;
      v = cf[(s * 36864 + wi) * 3 + g] * ss[wi];
    }
    wpk[((c2p * 9 + tap) * 64 + co) * 32 + ((q ^ ((co >> 1) & 3)) << 3) + e] = f2bf(v);
  }
}

// ---------------- kernel G: implicit GEMM, 2 blocks/CU TLP + setprio ----------------
// grid (32 b, 16 hg) = 512 blocks = 2/CU (LDS 75.3 KB). 4 waves/block; wave wid
// owns image row h0+wid: M=64 px x N=64 co, ALL 9 taps. Two independent blocks
// per CU drift in phase -> s_setprio(1) around each MFMA cluster lets the CU
// scheduler favor the MFMA-issuing wave over the co-block's staging waves (T5
// in its valid role-diverse regime; null in lockstep m190, +4-25% when diverse).
__global__ __launch_bounds__(256, 2) void gemm_k(
    const unsigned short* __restrict__ fg, const unsigned short* __restrict__ wpk,
    const float* __restrict__ bias, float* __restrict__ out) {
  extern __shared__ __align__(16) char smem[];
  const int b = blockIdx.x;
  const int h0 = blockIdx.y * 4;
  const int tid = threadIdx.x;
  const int lane = tid & 63;
  const int wid = tid >> 6;          // 0..3
  const int l15 = lane & 15;
  const int lg = lane >> 4;
  const char* fgB = (const char*)fg;
  const char* wpkB = (const char*)wpk;

  // zero never-staged bytes: halo cols + out-of-range rows (both feat buffers)
  for (int i = tid; i < 2 * FBUF4 / 4; i += 256) {
    int off = i * 4;
    int off2 = (off >= FBUF4) ? off - FBUF4 : off;
    int row = off2 / FROW;
    int cb = off2 - row * FROW;
    int hh = h0 - 1 + row;
    bool staged = ((unsigned)hh < 64u) && (cb >= 64) && (cb < 4160);
    if (!staged) ((int*)smem)[i] = 0;
  }

  // hoisted swizzled LDS offsets
  int aoff[4][3], boff[4];
#pragma unroll
  for (int cf = 0; cf < 4; ++cf) {
#pragma unroll
    for (int kw = 0; kw < 3; ++kw) {
      int col = cf * 16 + l15 + kw;
      aoff[cf][kw] = col * 64 + ((lg ^ ((col >> 1) & 3)) << 4);
    }
    int co = cf * 16 + l15;
    boff[cf] = co * 64 + ((lg ^ ((co >> 1) & 3)) << 4);
  }

  // stage B trio for (chunk cn, kh khn) into bdst: 12 gload16 over 4 waves
#define STAGE_TRIO(cn, khn, bdst)                                                \
  _Pragma("unroll")                                                              \
  for (int i = 0; i < 3; ++i) {                                                  \
    int u = i * 4 + wid;             /* 0..11: tap t=u>>2, part=u&3 */           \
    gload16(wpkB + (size_t)((cn) * 9 + (khn) * 3 + (u >> 2)) * 4096 +            \
                (u & 3) * 1024 + lane * 16,                                      \
            (bdst) + (u >> 2) * 4096 + (u & 3) * 1024);                          \
  }
  // stage 8 of 24 feature calls (rows 0..5 x 4 parts) for chunk cn, phase kh
#define STAGE_F8(cn, khp, fdst)                                                  \
  _Pragma("unroll")                                                              \
  for (int j = 0; j < 2; ++j) {                                                  \
    int k = (khp) * 8 + wid * 2 + j;  /* 0..23 */                                \
    int row = k >> 2, part = k & 3;                                              \
    int hh = h0 - 1 + row;                                                       \
    if ((unsigned)hh < 64u)                                                      \
      gload16(fgB + ((size_t)((cn) * 2048 + b * 64 + hh)) * 4096 +               \
                  part * 1024 + lane * 16,                                       \
              (fdst) + row * FROW + 64 + part * 1024);                           \
  }

  // prologue: feat chunk 0 (all 24) + B trio (0,0)
#pragma unroll
  for (int p = 0; p < 3; ++p) { STAGE_F8(0, p, smem) }
  STAGE_TRIO(0, 0, smem + 2 * FBUF4)
  __syncthreads();

  f32x4 acc[4][4];
#pragma unroll
  for (int cfi = 0; cfi < 4; ++cfi)
#pragma unroll
    for (int nf = 0; nf < 4; ++nf)
#pragma unroll
      for (int qq = 0; qq < 4; ++qq) acc[cfi][nf][qq] = 0.0f;

  for (int c2 = 0; c2 < 14; ++c2) {
    const char* f = smem + ((c2 & 1) ? FBUF4 : 0);
    char* fnext = smem + (((c2 + 1) & 1) ? FBUF4 : 0);
#pragma unroll
    for (int kh = 0; kh < 3; ++kh) {
      const int khg = c2 * 3 + kh;
      const char* bb = smem + 2 * FBUF4 + ((khg & 1) ? BTRIO : 0);
      // stage next B trio
      if (khg < 41) {
        char* bnext = smem + 2 * FBUF4 + (((khg + 1) & 1) ? BTRIO : 0);
        const int cn = (khg + 1) / 3, khn = (khg + 1) % 3;
        STAGE_TRIO(cn, khn, bnext)
      }
      // stage 8 feature calls for next chunk
      if (c2 < 13) { STAGE_F8(c2 + 1, kh, fnext) }

      const char* frow = f + (wid + kh) * FROW;
#pragma unroll
      for (int kw = 0; kw < 3; ++kw) {
        bf16x8 A[4], Bv[4];
#pragma unroll
        for (int cfi = 0; cfi < 4; ++cfi)
          A[cfi] = *(const bf16x8*)(frow + aoff[cfi][kw]);
#pragma unroll
        for (int nf = 0; nf < 4; ++nf)
          Bv[nf] = *(const bf16x8*)(bb + kw * 4096 + boff[nf]);
        __builtin_amdgcn_s_setprio(1);
#pragma unroll
        for (int cfi = 0; cfi < 4; ++cfi)
#pragma unroll
          for (int nf = 0; nf < 4; ++nf)
            acc[cfi][nf] = __builtin_amdgcn_mfma_f32_16x16x32_bf16(
                A[cfi], Bv[nf], acc[cfi][nf], 0, 0, 0);
        __builtin_amdgcn_s_setprio(0);
      }
      __syncthreads();
    }
  }
#undef STAGE_TRIO
#undef STAGE_F8

  // epilogue: direct store (wave owns full K). C/D: col(l15)=co, row=lg*4+reg=w
  const int h = h0 + wid;
#pragma unroll
  for (int cfi = 0; cfi < 4; ++cfi) {
    int w4 = cfi * 16 + (lg << 2);
#pragma unroll
    for (int nf = 0; nf < 4; ++nf) {
      int co = nf * 16 + l15;
      float bv = bias[co];
      f32x4 v = acc[cfi][nf];
      f32x4 res;
      res[0] = v[0] + bv; res[1] = v[1] + bv; res[2] = v[2] + bv; res[3] = v[3] + bv;
      *(f32x4*)(out + ((size_t)(b * 64 + co) * 64 + h) * 64 + w4) = res;
    }
  }
}

// ---------------- fallback: naive fp32 direct (if ws too small) ----------------
__global__ void naive_k(const float* __restrict__ x, const float* __restrict__ sb,
                        const float* __restrict__ ss, const float* __restrict__ cf,
                        const float* __restrict__ bias, float* __restrict__ out) {
  int idx = blockIdx.x * 256 + threadIdx.x;
  if (idx >= 32 * 64 * 64 * 64) return;
  int w = idx & 63, h = (idx >> 6) & 63, co = (idx >> 12) & 63, b = idx >> 18;
  float acc = bias[co];
  for (int ci = 0; ci < 64; ++ci) {
    for (int kh = 0; kh < 3; ++kh) {
      int hh = h + kh - 1;
      if ((unsigned)hh >= 64u) continue;
      for (int kw = 0; kw < 3; ++kw) {
        int ww = w + kw - 1;
        if ((unsigned)ww >= 64u) continue;
        float v = x[((b * 64 + ci) * 64 + hh) * 64 + ww];
        int wi = ((co * 64 + ci) * 3 + kh) * 3 + kw;
        float s1, c1; __sincosf(v, &s1, &c1);
        float c2 = c1 * c1 - s1 * s1, s2 = 2.f * s1 * c1;
        float c3 = c1 * c2 - s1 * s2, s3 = s1 * c2 + c1 * s2;
        float t = sb[wi] * (v / (1.f + __expf(-v)));
        t += ss[wi] * (cf[wi * 3] * c1 + cf[wi * 3 + 1] * c2 + cf[wi * 3 + 2] * c3 +
                       cf[(36864 + wi) * 3] * s1 + cf[(36864 + wi) * 3 + 1] * s2 +
                       cf[(36864 + wi) * 3 + 2] * s3);
        acc += t;
      }
    }
  }
  out[idx] = acc;
}

extern "C" void kernel_launch(void* const* d_in, const int* in_sizes, int n_in,
                              void* d_out, int out_size, void* d_ws, size_t ws_size,
                              hipStream_t stream) {
  const float* x = (const float*)d_in[0];
  const float* sb = (const float*)d_in[1];
  const float* ss = (const float*)d_in[2];
  const float* cf = (const float*)d_in[3];
  const float* bias = (const float*)d_in[4];
  float* out = (float*)d_out;

  const size_t FEATS_OFF = 1u << 20;                          // wpk in first 1 MB
  const size_t NEED = FEATS_OFF + (size_t)14 * 32 * 64 * 4096; // ~118.5 MB
  if (ws_size >= NEED) {
    unsigned short* wpk = (unsigned short*)d_ws;
    unsigned short* fg = (unsigned short*)((char*)d_ws + FEATS_OFF);
    feats_k<<<dim3(32, 64), 256, 0, stream>>>(x, sb, ss, cf, fg, wpk);
    (void)hipFuncSetAttribute((const void*)gemm_k,
                              hipFuncAttributeMaxDynamicSharedMemorySize, LDS_T2);
    gemm_k<<<dim3(32, 16), 256, LDS_T2, stream>>>(fg, wpk, bias, out);
  } else {
    naive_k<<<32768, 256, 0, stream>>>(x, sb, ss, cf, bias, out);
  }
}